// Round 2
// baseline (1057.747 us; speedup 1.0000x reference)
//
#include <hip/hip_runtime.h>
#include <hip/hip_bf16.h>

// Problem constants
#define HH 180      // hidden / feature size
#define TT 240      // timesteps
#define KP 192      // K padded to 6*32 for MFMA
#define MP 576      // 3 gate sections (i,g,o) x 192 rows
#define LSTR 194    // LDS k-stride (elements) -> 97 dwords, odd: 2-way-free banks
#define KOUT 43200  // T*H
#define BB 2048

typedef __attribute__((ext_vector_type(8))) short short8;
typedef __attribute__((ext_vector_type(4))) float float4v;

__device__ inline unsigned short f2bf(float f) {
    unsigned u = __builtin_bit_cast(unsigned, f);
    u += 0x7fffu + ((u >> 16) & 1u);          // round-to-nearest-even
    return (unsigned short)(u >> 16);
}
__device__ inline float bf2f(unsigned short h) {
    unsigned u = ((unsigned)h) << 16;
    return __builtin_bit_cast(float, u);
}
__device__ inline float sigm(float x) {
    return __builtin_amdgcn_rcpf(1.f + __expf(-x));
}
__device__ inline float tanh_(float x) {
    return 2.f * __builtin_amdgcn_rcpf(1.f + __expf(-2.f * x)) - 1.f;
}

// ---------------------------------------------------------------------------
// prep: build reordered/padded bf16 weights + fused biases + zero logits.
// W'[g*192+h][k] = W[(g==0?h:g==1?360+h:540+h)][k]  (i,g,o sections; f-gate dead)
// ---------------------------------------------------------------------------
__global__ void prep_kernel(const float* __restrict__ W1, const float* __restrict__ bi1,
                            const float* __restrict__ bh1, const float* __restrict__ W2,
                            const float* __restrict__ bi2, const float* __restrict__ bh2,
                            const float* __restrict__ Wo,
                            unsigned short* __restrict__ W1p, unsigned short* __restrict__ W2p,
                            float* __restrict__ bEp, float* __restrict__ bDp,
                            unsigned short* __restrict__ Wop, float* __restrict__ logits)
{
    int id = blockIdx.x * 256 + threadIdx.x;
    if (id < MP * KP) {
        int mp = id / KP, k = id % KP;
        int g = mp / KP, h = mp % KP;   // note MP/3 == KP == 192
        unsigned short v1 = 0, v2 = 0;
        if (h < HH && k < HH) {
            int r = (g == 0) ? h : (g == 1 ? 360 + h : 540 + h);
            v1 = f2bf(W1[r * HH + k]);
            v2 = f2bf(W2[r * HH + k]);
        }
        W1p[id] = v1; W2p[id] = v2;
    }
    if (id < MP) {
        int g = id / KP, h = id % KP;
        float v1 = 0.f, v2 = 0.f;
        if (h < HH) {
            int r = (g == 0) ? h : (g == 1 ? 360 + h : 540 + h);
            v1 = bi1[r] + bh1[r];
            v2 = bi2[r] + bh2[r];
        }
        bEp[id] = v1; bDp[id] = v2;
    }
    if (id < 48 * KOUT) {
        int n = id / KOUT, k = id % KOUT;
        Wop[id] = (n < 40) ? f2bf(Wo[n * KOUT + k]) : (unsigned short)0;
    }
    if (id < BB * 40) logits[id] = 0.f;
}

// ---------------------------------------------------------------------------
// phaseA: fused encoder GEMM -> gates -> exp(h_enc) -> decoder GEMM -> h_dec.
// Block: one b, 128 t-columns (t0 in {0,112}). 4 waves:
//   wave = (colhalf<<1)|parity : colhalf -> cols [64*ch,+64), parity -> odd/even triplets.
// A-frags (W') stream global->VGPR (L2 resident). B-frags (x / E) preloaded from LDS.
// Softmax scale folded into GEMM2 epilogue (per-column 1/sum).
// ---------------------------------------------------------------------------
__global__ __launch_bounds__(256, 2) void phaseA_kernel(
    const float* __restrict__ x, const unsigned short* __restrict__ W1p,
    const unsigned short* __restrict__ W2p, const float* __restrict__ bEp,
    const float* __restrict__ bDp, unsigned short* __restrict__ hdec)
{
    __shared__ __align__(16) unsigned short Xs[128 * LSTR];
    __shared__ float bEs[MP], bDs[MP], sred[256];

    const int tid = threadIdx.x;
    const int b = blockIdx.x >> 1;
    const int t0 = (blockIdx.x & 1) * 112;
    const float* xb = x + (size_t)b * HH * TT;

    // FIX(R1): MP=576 > blockDim=256 -> must stride, else bEs/bDs[256:576]
    // (g-gate and o-gate biases) are uninitialized garbage.
    for (int i = tid; i < MP; i += 256) { bEs[i] = bEp[i]; bDs[i] = bDp[i]; }

    // ---- stage x[b][:,t0:t0+128] as bf16 into Xs[col][k] -------------------
    {
        const int c = tid & 127, half = tid >> 7;
        unsigned* lu = (unsigned*)Xs;
        const int cbase = c * (LSTR / 2);        // 97 dwords per column-row
        for (int i = 0; i < 45; ++i) {
            int f = half * 90 + 2 * i;
            float a0 = xb[f * TT + t0 + c];
            float a1 = xb[(f + 1) * TT + t0 + c];
            lu[cbase + (f >> 1)] = (unsigned)f2bf(a0) | ((unsigned)f2bf(a1) << 16);
        }
        if (half == 0) {                          // zero k-pad 180..193 (NaN guard)
            for (int j = 0; j < 7; ++j) lu[cbase + 90 + j] = 0u;
        }
    }
    __syncthreads();

    const int lane = tid & 63, wv = tid >> 6;
    const int ch = wv >> 1, par = wv & 1;
    const int l15 = lane & 15, l4 = lane >> 4;

    // ---- preload B1 fragments (x tiles) into registers ---------------------
    short8 Bf[4][6];
    {
        const unsigned* lu = (const unsigned*)Xs;
        for (int nt = 0; nt < 4; ++nt) {
            int col = ch * 64 + nt * 16 + l15;
            int base = col * (LSTR / 2) + l4 * 4;    // k elems 8*l4 -> 4 dwords
            #pragma unroll
            for (int ks = 0; ks < 6; ++ks) {
                union { unsigned u[4]; short8 v; } t;
                int idx = base + ks * 16;
                t.u[0] = lu[idx]; t.u[1] = lu[idx + 1];
                t.u[2] = lu[idx + 2]; t.u[3] = lu[idx + 3];
                Bf[nt][ks] = t.v;
            }
        }
    }
    __syncthreads();   // everyone's B1 frags loaded before E overwrites Xs

    // ---- GEMM1: gates = W1' @ x ; epilogue -> E = exp(h_enc) in LDS --------
    {
        const uint4* W1q = (const uint4*)W1p;     // 8 bf16 per uint4, row stride 192 elems = 24 q
        for (int tri = par; tri < 12; tri += 2) {
            float4v acc[3][4];
            #pragma unroll
            for (int s = 0; s < 3; ++s)
                #pragma unroll
                for (int n = 0; n < 4; ++n) acc[s][n] = (float4v){0.f, 0.f, 0.f, 0.f};
            #pragma unroll
            for (int sec = 0; sec < 3; ++sec) {
                int abase = (sec * KP + tri * 16 + l15) * (KP / 8) + l4;
                #pragma unroll
                for (int ks = 0; ks < 6; ++ks) {
                    union { uint4 q; short8 v; } a;
                    a.q = W1q[abase + ks * 4];
                    #pragma unroll
                    for (int nt = 0; nt < 4; ++nt)
                        acc[sec][nt] = __builtin_amdgcn_mfma_f32_16x16x32_bf16(
                            a.v, Bf[nt][ks], acc[sec][nt], 0, 0, 0);
                }
            }
            // epilogue: i/g/o -> h_enc -> E (unnormalized softmax numerator)
            unsigned* lw = (unsigned*)Xs;
            const int h0 = tri * 16 + l4 * 4;
            #pragma unroll
            for (int nt = 0; nt < 4; ++nt) {
                int col = ch * 64 + nt * 16 + l15;
                unsigned pk[2];
                #pragma unroll
                for (int e = 0; e < 4; ++e) {
                    int h = h0 + e;
                    float gi = acc[0][nt][e] + bEs[h];
                    float gg = acc[1][nt][e] + bEs[KP + h];
                    float go = acc[2][nt][e] + bEs[2 * KP + h];
                    float cc = sigm(gi) * tanh_(gg);
                    float hv = sigm(go) * tanh_(cc);
                    ((unsigned short*)pk)[e] = f2bf(__expf(hv));
                }
                lw[col * (LSTR / 2) + (h0 >> 1)] = pk[0];
                lw[col * (LSTR / 2) + (h0 >> 1) + 1] = pk[1];
            }
        }
    }
    __syncthreads();

    // ---- per-column sum of E (softmax denominator) -------------------------
    {
        const int c = tid & 127, half = tid >> 7;
        const unsigned* lu = (const unsigned*)Xs;
        int base = c * (LSTR / 2) + half * 45;    // elems [90*half, +90)
        float s = 0.f;
        for (int j = 0; j < 45; ++j) {
            unsigned u = lu[base + j];
            s += bf2f((unsigned short)u) + bf2f((unsigned short)(u >> 16));
        }
        sred[half * 128 + c] = s;
    }
    __syncthreads();

    // ---- preload B2 fragments (E tiles) + per-column 1/sum -----------------
    {
        const unsigned* lu = (const unsigned*)Xs;
        for (int nt = 0; nt < 4; ++nt) {
            int col = ch * 64 + nt * 16 + l15;
            int base = col * (LSTR / 2) + l4 * 4;
            #pragma unroll
            for (int ks = 0; ks < 6; ++ks) {
                union { unsigned u[4]; short8 v; } t;
                int idx = base + ks * 16;
                t.u[0] = lu[idx]; t.u[1] = lu[idx + 1];
                t.u[2] = lu[idx + 2]; t.u[3] = lu[idx + 3];
                Bf[nt][ks] = t.v;
            }
        }
    }
    float rs[4];
    #pragma unroll
    for (int nt = 0; nt < 4; ++nt) {
        int col = ch * 64 + nt * 16 + l15;
        rs[nt] = __builtin_amdgcn_rcpf(sred[col] + sred[128 + col]);
    }

    // ---- GEMM2: gates2 = (W2' @ E) * rs + b ; epilogue -> h_dec (global) ---
    {
        const uint4* W2q = (const uint4*)W2p;
        unsigned short* hout = hdec + (size_t)b * TT * HH;
        for (int tri = par; tri < 12; tri += 2) {
            float4v acc[3][4];
            #pragma unroll
            for (int s = 0; s < 3; ++s)
                #pragma unroll
                for (int n = 0; n < 4; ++n) acc[s][n] = (float4v){0.f, 0.f, 0.f, 0.f};
            #pragma unroll
            for (int sec = 0; sec < 3; ++sec) {
                int abase = (sec * KP + tri * 16 + l15) * (KP / 8) + l4;
                #pragma unroll
                for (int ks = 0; ks < 6; ++ks) {
                    union { uint4 q; short8 v; } a;
                    a.q = W2q[abase + ks * 4];
                    #pragma unroll
                    for (int nt = 0; nt < 4; ++nt)
                        acc[sec][nt] = __builtin_amdgcn_mfma_f32_16x16x32_bf16(
                            a.v, Bf[nt][ks], acc[sec][nt], 0, 0, 0);
                }
            }
            const int h0 = tri * 16 + l4 * 4;
            if (h0 < HH) {                         // skip 180..191 pad quads
                #pragma unroll
                for (int nt = 0; nt < 4; ++nt) {
                    int col = ch * 64 + nt * 16 + l15;
                    unsigned pk[2];
                    #pragma unroll
                    for (int e = 0; e < 4; ++e) {
                        int h = h0 + e;
                        float gi = acc[0][nt][e] * rs[nt] + bDs[h];
                        float gg = acc[1][nt][e] * rs[nt] + bDs[KP + h];
                        float go = acc[2][nt][e] * rs[nt] + bDs[2 * KP + h];
                        float cc = sigm(gi) * tanh_(gg);
                        float hv = sigm(go) * tanh_(cc);
                        ((unsigned short*)pk)[e] = f2bf(hv);
                    }
                    uint2 pv; pv.x = pk[0]; pv.y = pk[1];
                    *(uint2*)(hout + (size_t)(t0 + col) * HH + h0) = pv;
                }
            }
        }
    }
}

// ---------------------------------------------------------------------------
// phaseB: logits += hdec[2048 x 43200] @ Wo'^T[43200 x 48] (K-split, atomics)
// grid (32 M-blocks, 30 K-chunks of 1440); block 4 waves x 16 rows x 48 cols.
// ---------------------------------------------------------------------------
__global__ __launch_bounds__(256, 4) void phaseB_kernel(
    const unsigned short* __restrict__ hdec, const unsigned short* __restrict__ Wop,
    float* __restrict__ logits)
{
    const int tid = threadIdx.x;
    const int lane = tid & 63, wv = tid >> 6;
    const int l15 = lane & 15, l4 = lane >> 4;
    const int m0 = blockIdx.x * 64 + wv * 16;
    const int k0 = blockIdx.y * 1440;

    const uint4* Aq = (const uint4*)hdec;
    const uint4* Bq = (const uint4*)Wop;
    const int QK = KOUT / 8;                     // 5400 uint4 per row
    int abase = (m0 + l15) * QK + (k0 >> 3) + l4;
    int bbase = l15 * QK + (k0 >> 3) + l4;

    float4v acc[3];
    #pragma unroll
    for (int n = 0; n < 3; ++n) acc[n] = (float4v){0.f, 0.f, 0.f, 0.f};

    #pragma unroll 3
    for (int ks = 0; ks < 45; ++ks) {
        union { uint4 q; short8 v; } a, b0, b1, b2;
        a.q  = Aq[abase + ks * 4];
        b0.q = Bq[bbase + ks * 4];
        b1.q = Bq[bbase + 16 * QK + ks * 4];
        b2.q = Bq[bbase + 32 * QK + ks * 4];
        acc[0] = __builtin_amdgcn_mfma_f32_16x16x32_bf16(a.v, b0.v, acc[0], 0, 0, 0);
        acc[1] = __builtin_amdgcn_mfma_f32_16x16x32_bf16(a.v, b1.v, acc[1], 0, 0, 0);
        acc[2] = __builtin_amdgcn_mfma_f32_16x16x32_bf16(a.v, b2.v, acc[2], 0, 0, 0);
    }

    #pragma unroll
    for (int nt = 0; nt < 3; ++nt) {
        int o = nt * 16 + l15;
        if (o < 40) {
            #pragma unroll
            for (int e = 0; e < 4; ++e) {
                int row = m0 + l4 * 4 + e;
                atomicAdd(&logits[row * 40 + o], acc[nt][e]);
            }
        }
    }
}

// ---------------------------------------------------------------------------
// outK: out[b][j][:] = softmax(logits[b][10j..10j+9] + b_out)
// ---------------------------------------------------------------------------
__global__ void out_kernel(const float* __restrict__ logits, const float* __restrict__ bout,
                           float* __restrict__ out)
{
    int id = blockIdx.x * 256 + threadIdx.x;
    if (id >= BB * 4) return;
    int b = id >> 2, j = id & 3;
    float v[10], mx = -1e30f;
    #pragma unroll
    for (int d = 0; d < 10; ++d) {
        v[d] = logits[b * 40 + j * 10 + d] + bout[j * 10 + d];
        mx = fmaxf(mx, v[d]);
    }
    float s = 0.f;
    #pragma unroll
    for (int d = 0; d < 10; ++d) { v[d] = __expf(v[d] - mx); s += v[d]; }
    float r = __builtin_amdgcn_rcpf(s);
    #pragma unroll
    for (int d = 0; d < 10; ++d) out[b * 40 + j * 10 + d] = v[d] * r;
}

// ---------------------------------------------------------------------------
extern "C" void kernel_launch(void* const* d_in, const int* in_sizes, int n_in,
                              void* d_out, int out_size, void* d_ws, size_t ws_size,
                              hipStream_t stream)
{
    const float* x    = (const float*)d_in[0];
    const float* W1   = (const float*)d_in[1];
    const float* bi1  = (const float*)d_in[2];
    const float* bh1  = (const float*)d_in[3];
    const float* W2   = (const float*)d_in[4];
    const float* bi2  = (const float*)d_in[5];
    const float* bh2  = (const float*)d_in[6];
    const float* Wo   = (const float*)d_in[7];
    const float* bout = (const float*)d_in[8];

    // workspace carve (all offsets 512B-aligned); total ~173.5 MiB
    char* ws = (char*)d_ws;
    unsigned short* W1p = (unsigned short*)(ws + 0);          // 576*192*2 = 221184
    unsigned short* W2p = (unsigned short*)(ws + 221184);     // 221184
    float* bEp          = (float*)(ws + 442368);              // 2304 (+pad)
    float* bDp          = (float*)(ws + 444928);              // 2304 (+pad)
    unsigned short* Wop = (unsigned short*)(ws + 447488);     // 48*43200*2 = 4147200
    float* logits       = (float*)(ws + 4594688);             // 2048*40*4 = 327680
    unsigned short* hdec= (unsigned short*)(ws + 4922368);    // 2048*240*180*2

    prep_kernel<<<(48 * KOUT + 255) / 256, 256, 0, stream>>>(
        W1, bi1, bh1, W2, bi2, bh2, Wo, W1p, W2p, bEp, bDp, Wop, logits);
    phaseA_kernel<<<BB * 2, 256, 0, stream>>>(x, W1p, W2p, bEp, bDp, hdec);
    phaseB_kernel<<<dim3(32, 30), 256, 0, stream>>>(hdec, Wop, logits);
    out_kernel<<<(BB * 4 + 255) / 256, 256, 0, stream>>>(logits, bout, (float*)d_out);
}